// Round 10
// baseline (89.060 us; speedup 1.0000x reference)
//
#include <hip/hip_runtime.h>
#include <hip/hip_fp16.h>
#include <math.h>

#define BATCH 4
#define SEQ   512
#define IND   256
#define NH    8
#define DKV   32
#define BH    32   // BATCH*NH
#define NTOK  2048 // BATCH*SEQ

typedef __attribute__((ext_vector_type(8))) short short8v;
typedef __attribute__((ext_vector_type(4))) float floatx4;

__device__ __forceinline__ unsigned f2bf1(float f) {
    unsigned u = __builtin_bit_cast(unsigned, f);
    return (u + 0x7fffu + ((u >> 16) & 1u)) >> 16;
}
__device__ __forceinline__ unsigned f2bf2(float lo, float hi) {
    return f2bf1(lo) | (f2bf1(hi) << 16);
}
__device__ __forceinline__ __half2 habs2_(__half2 x) {
    unsigned u = __builtin_bit_cast(unsigned, x) & 0x7fff7fffu;
    return __builtin_bit_cast(__half2, u);
}

// ============ Kernel 1: fused LayerNorm + Q/K/V projections (bf16 MFMA) =====
// grid (32, 12): x = 64-row tile, y: which = y>>2 (0=q,1=k,2=v), n0 = (y&3)*64
// Q,K: f16 [bh][l][32].  V: bf16 TRANSPOSED [bh][d][512].
__global__ __launch_bounds__(256) void lnproj_kernel(
        const float* __restrict__ x,
        const float* __restrict__ gamma, const float* __restrict__ beta,
        const float* __restrict__ wq, const float* __restrict__ wk,
        const float* __restrict__ wv,
        float* __restrict__ xn, float* __restrict__ am, float* __restrict__ R,
        __half* __restrict__ Q, __half* __restrict__ K,
        unsigned short* __restrict__ Vt) {
    __shared__ __align__(16) unsigned short As[64][264];   // [m][k] bf16, full K
    __shared__ __align__(16) unsigned short Bs[2][64][40]; // [n][k] bf16, K-tile 32
    const int t = threadIdx.x;
    const int m0 = blockIdx.x * 64;
    const int y = blockIdx.y;
    const int which = y >> 2;
    const int n0 = (y & 3) * 64;
    const float* W = (which == 0) ? wq : (which == 1) ? wk : wv;

    // ---- Phase A: LayerNorm rows m0..m0+63 -> As (bf16) ----
    {
        const int r = t >> 2, q = t & 3;
        const float* xr = x + (m0 + r) * IND + q * 64;
        float4 xv[16];
        float s = 0.0f, s2 = 0.0f;
        #pragma unroll
        for (int i = 0; i < 16; i++) {
            xv[i] = *(const float4*)&xr[i * 4];
            s  += xv[i].x + xv[i].y + xv[i].z + xv[i].w;
            s2 += xv[i].x * xv[i].x + xv[i].y * xv[i].y
                + xv[i].z * xv[i].z + xv[i].w * xv[i].w;
        }
        s  += __shfl_xor(s, 1, 64);  s  += __shfl_xor(s, 2, 64);
        s2 += __shfl_xor(s2, 1, 64); s2 += __shfl_xor(s2, 2, 64);
        float mu = s * (1.0f / IND);
        float var = s2 * (1.0f / IND) - mu * mu;
        float rinv = rsqrtf(var + 1e-6f);
        const bool dox = (y == 0);
        if (dox) {
            if (t < 64) am[m0 + t] = 0.0f;
            R[blockIdx.x * 512 + t] = 0.0f;          // zero rowsum accumulator
            R[blockIdx.x * 512 + 256 + t] = 0.0f;
        }
        #pragma unroll
        for (int i = 0; i < 8; i++) {
            float4 a = xv[2 * i], bv = xv[2 * i + 1];
            float4 g0 = *(const float4*)&gamma[q * 64 + i * 8];
            float4 g1 = *(const float4*)&gamma[q * 64 + i * 8 + 4];
            float4 b0 = *(const float4*)&beta[q * 64 + i * 8];
            float4 b1 = *(const float4*)&beta[q * 64 + i * 8 + 4];
            float4 n0v, n1v;
            n0v.x = (a.x - mu) * rinv * g0.x + b0.x;
            n0v.y = (a.y - mu) * rinv * g0.y + b0.y;
            n0v.z = (a.z - mu) * rinv * g0.z + b0.z;
            n0v.w = (a.w - mu) * rinv * g0.w + b0.w;
            n1v.x = (bv.x - mu) * rinv * g1.x + b1.x;
            n1v.y = (bv.y - mu) * rinv * g1.y + b1.y;
            n1v.z = (bv.z - mu) * rinv * g1.z + b1.z;
            n1v.w = (bv.w - mu) * rinv * g1.w + b1.w;
            if (dox) {
                *(float4*)&xn[(m0 + r) * IND + q * 64 + i * 8] = n0v;
                *(float4*)&xn[(m0 + r) * IND + q * 64 + i * 8 + 4] = n1v;
            }
            uint4 pk;
            pk.x = f2bf2(n0v.x, n0v.y); pk.y = f2bf2(n0v.z, n0v.w);
            pk.z = f2bf2(n1v.x, n1v.y); pk.w = f2bf2(n1v.z, n1v.w);
            *(uint4*)&As[r][q * 64 + i * 8] = pk;
        }
    }

    // ---- Phase B: MFMA over K (B double-buffered per 32-k tile) ----
    const int w = t >> 6, l = t & 63;
    const int wm = (w >> 1) * 32, wn = (w & 1) * 32;
    const int fr = l & 15, fg = l >> 4;
    floatx4 acc[2][2];
    #pragma unroll
    for (int i = 0; i < 2; i++)
        #pragma unroll
        for (int j = 0; j < 2; j++) acc[i][j] = (floatx4)(0.0f);

    const int kl = t >> 4, nq = t & 15;
    auto stageB = [&](int kt, int buf) {
        float4 b0 = *(const float4*)&W[(kt * 32 + kl) * IND + n0 + nq * 4];
        float4 b1 = *(const float4*)&W[(kt * 32 + 16 + kl) * IND + n0 + nq * 4];
        Bs[buf][nq * 4 + 0][kl] = (unsigned short)f2bf1(b0.x);
        Bs[buf][nq * 4 + 1][kl] = (unsigned short)f2bf1(b0.y);
        Bs[buf][nq * 4 + 2][kl] = (unsigned short)f2bf1(b0.z);
        Bs[buf][nq * 4 + 3][kl] = (unsigned short)f2bf1(b0.w);
        Bs[buf][nq * 4 + 0][kl + 16] = (unsigned short)f2bf1(b1.x);
        Bs[buf][nq * 4 + 1][kl + 16] = (unsigned short)f2bf1(b1.y);
        Bs[buf][nq * 4 + 2][kl + 16] = (unsigned short)f2bf1(b1.z);
        Bs[buf][nq * 4 + 3][kl + 16] = (unsigned short)f2bf1(b1.w);
    };
    stageB(0, 0);
    __syncthreads();
    #pragma unroll
    for (int kt = 0; kt < 8; kt++) {
        if (kt < 7) stageB(kt + 1, (kt + 1) & 1);
        const int buf = kt & 1;
        short8v a0 = *(const short8v*)&As[wm + fr][kt * 32 + fg * 8];
        short8v a1 = *(const short8v*)&As[wm + 16 + fr][kt * 32 + fg * 8];
        short8v b0 = *(const short8v*)&Bs[buf][wn + fr][fg * 8];
        short8v b1 = *(const short8v*)&Bs[buf][wn + 16 + fr][fg * 8];
        acc[0][0] = __builtin_amdgcn_mfma_f32_16x16x32_bf16(a0, b0, acc[0][0], 0, 0, 0);
        acc[0][1] = __builtin_amdgcn_mfma_f32_16x16x32_bf16(a0, b1, acc[0][1], 0, 0, 0);
        acc[1][0] = __builtin_amdgcn_mfma_f32_16x16x32_bf16(a1, b0, acc[1][0], 0, 0, 0);
        acc[1][1] = __builtin_amdgcn_mfma_f32_16x16x32_bf16(a1, b1, acc[1][1], 0, 0, 0);
        __syncthreads();
    }

    // ---- Epilogue ----
    const float scale = (which == 0) ? 0.17677669529663687f : 1.0f;
    #pragma unroll
    for (int mi = 0; mi < 2; mi++)
        #pragma unroll
        for (int ni = 0; ni < 2; ni++)
            #pragma unroll
            for (int reg = 0; reg < 4; reg++) {
                int row = m0 + wm + mi * 16 + fg * 4 + reg;   // token
                int col = n0 + wn + ni * 16 + fr;             // 0..255
                int b = row >> 9, ll = row & 511;
                int h = col >> 5, d = col & 31;
                if (which == 2) {
                    Vt[(((b << 3) + h) * DKV + d) * SEQ + ll] =
                        (unsigned short)f2bf1(acc[mi][ni][reg]);
                } else {
                    __half* O = (which == 0) ? Q : K;
                    O[(((b << 3) + h) * SEQ + ll) * DKV + d] =
                        __float2half_rn(acc[mi][ni][reg] * scale);
                }
            }
}

// ============ Kernel 2a: score pass ==========================================
// grid (32, 32, 2): x = 16-row i-tile, y = bh, z = 256-j half. block 256.
// Thread (g=t>>5, jl=t&31) owns rows {i0+g, i0+g+8}; j = jz + tile*128 + m*32 + jl.
// e = exp(score) directly (scores in [0,~2] => no max pass needed; partials
// combine by pure addition). e -> Pg bf16; rowsums -> atomicAdd R.
__global__ __launch_bounds__(256) void attn_score_kernel(
        const __half* __restrict__ Qh, const __half* __restrict__ Kh,
        unsigned short* __restrict__ Pg,   // [bh][512][512] bf16 e-values
        float* __restrict__ R) {           // [bh][512] rowsums
    __shared__ __align__(16) __half Th[2][128][40];   // 20.5 KB
    const int t = threadIdx.x;
    const int g = t >> 5, jl = t & 31;
    const int gy = blockIdx.y;
    const int i0 = blockIdx.x * 16;
    const int jz = blockIdx.z * 256;
    const __half* Qb = Qh + gy * SEQ * DKV;
    const __half* Kb = Kh + gy * SEQ * DKV;
    const int r0 = t >> 2, ch = t & 3;

    // K rows (i0+g, i0+g+8) in registers as half2
    __half2 ka[16], kb[16];
    {
        const float4* pa = (const float4*)(Kb + (i0 + g) * DKV);
        const float4* pb = (const float4*)(Kb + (i0 + g + 8) * DKV);
        #pragma unroll
        for (int c = 0; c < 4; c++) {
            float4 va = pa[c], vb = pb[c];
            const __half2* ha = (const __half2*)&va;
            const __half2* hb = (const __half2*)&vb;
            #pragma unroll
            for (int k = 0; k < 4; k++) { ka[c*4+k] = ha[k]; kb[c*4+k] = hb[k]; }
        }
    }

    float vals_a[8], vals_b[8];
    float4 pre0, pre1;

    // ---- scores over 256 j (2 tiles of 128, double-buffered) ----
    pre0 = *(const float4*)(Qb + (jz + r0) * DKV + ch * 8);
    pre1 = *(const float4*)(Qb + (jz + r0 + 64) * DKV + ch * 8);
    *(float4*)&Th[0][r0][ch * 8] = pre0;
    *(float4*)&Th[0][r0 + 64][ch * 8] = pre1;
    __syncthreads();
    #pragma unroll
    for (int tile = 0; tile < 2; tile++) {
        const int buf = tile & 1;
        if (tile < 1) {
            pre0 = *(const float4*)(Qb + (jz + 128 + r0) * DKV + ch * 8);
            pre1 = *(const float4*)(Qb + (jz + 128 + r0 + 64) * DKV + ch * 8);
        }
        #pragma unroll
        for (int m = 0; m < 4; m++) {
            const int j = jl + m * 32;
            __half2 z = __float2half2_rn(0.0f);
            __half2 sa0 = z, sa1 = z, sb0 = z, sb1 = z;
            #pragma unroll
            for (int c = 0; c < 4; c++) {
                float4 qv = *(const float4*)&Th[buf][j][c * 8];
                const __half2* q2 = (const __half2*)&qv;
                #pragma unroll
                for (int k = 0; k < 4; k++) {
                    __half2 da = habs2_(__hsub2(q2[k], ka[c*4+k]));
                    __half2 db = habs2_(__hsub2(q2[k], kb[c*4+k]));
                    if (k & 1) { sa1 = __hadd2(sa1, da); sb1 = __hadd2(sb1, db); }
                    else       { sa0 = __hadd2(sa0, da); sb0 = __hadd2(sb0, db); }
                }
            }
            __half2 sa = __hadd2(sa0, sa1), sb = __hadd2(sb0, sb1);
            vals_a[tile*4+m] = (__low2float(sa) + __high2float(sa)) * (1.0f/32.0f);
            vals_b[tile*4+m] = (__low2float(sb) + __high2float(sb)) * (1.0f/32.0f);
        }
        if (tile < 1) {
            *(float4*)&Th[buf ^ 1][r0][ch * 8] = pre0;
            *(float4*)&Th[buf ^ 1][r0 + 64][ch * 8] = pre1;
        }
        __syncthreads();
    }

    // ---- exp (no max) + partial rowsums ----
    float sua = 0.0f, sub = 0.0f;
    #pragma unroll
    for (int m = 0; m < 8; m++) {
        vals_a[m] = __expf(vals_a[m]); sua += vals_a[m];
        vals_b[m] = __expf(vals_b[m]); sub += vals_b[m];
    }
    #pragma unroll
    for (int s = 1; s <= 16; s <<= 1) {
        sua += __shfl_xor(sua, s, 64);
        sub += __shfl_xor(sub, s, 64);
    }
    if (jl == 0) {
        atomicAdd(&R[gy * SEQ + i0 + g], sua);
        atomicAdd(&R[gy * SEQ + i0 + g + 8], sub);
    }

    // ---- store e (bf16) to Pg ----
    unsigned short* Pa = Pg + (gy * SEQ + i0 + g) * SEQ;
    unsigned short* Pb = Pg + (gy * SEQ + i0 + g + 8) * SEQ;
    #pragma unroll
    for (int m = 0; m < 8; m++) {
        const int j = jz + (m >> 2) * 128 + (m & 3) * 32 + jl;
        Pa[j] = (unsigned short)f2bf1(vals_a[m]);
        Pb[j] = (unsigned short)f2bf1(vals_b[m]);
    }
}

// ============ Kernel 2b: PV pass =============================================
// grid (32, 32): x = 16-row i-tile, y = bh. block 256 = 4 waves.
// Stage e-rows [16][512] bf16 -> Pl; MFMA PV (each wave full O, stores quarter,
// scaled by 1/R at store); am colsum weighted by 1/R.
__global__ __launch_bounds__(256) void attn_pv_kernel(
        const unsigned short* __restrict__ Pg, const float* __restrict__ R,
        const unsigned short* __restrict__ Vt,
        float* __restrict__ attn_out, float* __restrict__ am) {
    __shared__ __align__(16) unsigned short Pl[16][520];   // 16.6 KB
    __shared__ float Rv[16];
    const int t = threadIdx.x;
    const int l = t & 63, w = t >> 6;
    const int li = l & 15, jc = l >> 4;
    const int gy = blockIdx.y;
    const int i0 = blockIdx.x * 16;
    const int b = gy >> 3, h = gy & 7;
    const unsigned short* Vb = Vt + gy * DKV * SEQ;

    // ---- stage P rows + rinv ----
    {
        const unsigned short* Ps = Pg + (gy * SEQ + i0) * SEQ;
        const int row = t >> 4;
        #pragma unroll
        for (int k = 0; k < 4; k++) {
            const int chunk = (t & 15) + 16 * k;   // 16B chunks (8 u16)
            *(uint4*)&Pl[row][chunk * 8] =
                *(const uint4*)&Ps[row * SEQ + chunk * 8];
        }
    }
    if (t < 16) Rv[t] = 1.0f / R[gy * SEQ + i0 + t];
    __syncthreads();

    // ---- PV via MFMA: each wave computes full O[16][32], stores quarter ----
    floatx4 oacc[2];
    oacc[0] = (floatx4)(0.0f); oacc[1] = (floatx4)(0.0f);
    #pragma unroll
    for (int jt = 0; jt < 16; jt++) {
        short8v pa = *(const short8v*)&Pl[li][jt * 32 + jc * 8];
        #pragma unroll
        for (int n = 0; n < 2; n++) {
            short8v bf = *(const short8v*)&Vb[(n * 16 + li) * SEQ + jt * 32 + jc * 8];
            oacc[n] = __builtin_amdgcn_mfma_f32_16x16x32_bf16(pa, bf, oacc[n], 0, 0, 0);
        }
    }
    // D layout: col = l&15 = li (d), row = jc*4 + reg (i). Wave w stores jc==w.
    if (jc == w) {
        #pragma unroll
        for (int r = 0; r < 4; r++) {
            const float rinv = Rv[jc * 4 + r];
            #pragma unroll
            for (int n = 0; n < 2; n++)
                attn_out[(b * SEQ + i0 + jc * 4 + r) * IND + h * 32 + n * 16 + li] =
                    oacc[n][r] * rinv;
        }
    }

    // ---- am colsum (P normalized by rinv) + atomics ----
    {
        const int jp = t * 2;
        float cs0 = 0.0f, cs1 = 0.0f;
        #pragma unroll
        for (int i = 0; i < 16; i++) {
            unsigned u = *(const unsigned*)&Pl[i][jp];
            const float ri = Rv[i];
            cs0 += __builtin_bit_cast(float, u << 16) * ri;
            cs1 += __builtin_bit_cast(float, u & 0xffff0000u) * ri;
        }
        atomicAdd(&am[b * SEQ + jp],     cs0 * 0.125f);
        atomicAdd(&am[b * SEQ + jp + 1], cs1 * 0.125f);
    }
}

// ============ Kernel 3: FC(bf16 MFMA) + residual, + fused amnorm ============
// grid (33, 4): x<32 -> GEMM tile (m0=x*64, n0=y*64); x==32 -> amnorm batch y
__global__ __launch_bounds__(256) void fcam_kernel(
        const float* __restrict__ ao, const float* __restrict__ wfc,
        const float* __restrict__ xn, const float* __restrict__ am,
        float* __restrict__ out, float* __restrict__ out_am) {
    __shared__ __align__(16) unsigned short As[64][264];
    __shared__ __align__(16) unsigned short Bs[2][64][40];
    __shared__ float lmn[4], lmx[4];
    const int t = threadIdx.x;

    if (blockIdx.x == 32) {   // ---- amnorm for batch blockIdx.y ----
        int b = blockIdx.y;
        float v0 = am[b * SEQ + t];
        float v1 = am[b * SEQ + t + 256];
        float mn = fminf(v0, v1), mx = fmaxf(v0, v1);
        #pragma unroll
        for (int o = 32; o > 0; o >>= 1) {
            mn = fminf(mn, __shfl_xor(mn, o, 64));
            mx = fmaxf(mx, __shfl_xor(mx, o, 64));
        }
        int w = t >> 6;
        if ((t & 63) == 0) { lmn[w] = mn; lmx[w] = mx; }
        __syncthreads();
        mn = fminf(fminf(lmn[0], lmn[1]), fminf(lmn[2], lmn[3]));
        mx = fmaxf(fmaxf(lmx[0], lmx[1]), fmaxf(lmx[2], lmx[3]));
        float inv = 1.0f / (mx - mn);
        out_am[b * SEQ + t]       = (v0 - mn) * inv;
        out_am[b * SEQ + t + 256] = (v1 - mn) * inv;
        return;
    }

    const int m0 = blockIdx.x * 64;
    const int n0 = blockIdx.y * 64;

    {
        const int r = t >> 2, q = t & 3;
        const float* ar = ao + (m0 + r) * IND + q * 64;
        #pragma unroll
        for (int i = 0; i < 8; i++) {
            float4 a = *(const float4*)&ar[i * 8];
            float4 bv = *(const float4*)&ar[i * 8 + 4];
            uint4 pk;
            pk.x = f2bf2(a.x, a.y);  pk.y = f2bf2(a.z, a.w);
            pk.z = f2bf2(bv.x, bv.y); pk.w = f2bf2(bv.z, bv.w);
            *(uint4*)&As[r][q * 64 + i * 8] = pk;
        }
    }

    const int w = t >> 6, l = t & 63;
    const int wm = (w >> 1) * 32, wn = (w & 1) * 32;
    const int fr = l & 15, fg = l >> 4;
    floatx4 acc[2][2];
    #pragma unroll
    for (int i = 0; i < 2; i++)
        #pragma unroll
        for (int j = 0; j < 2; j++) acc[i][j] = (floatx4)(0.0f);

    const int kl = t >> 4, nq = t & 15;
    auto stageB = [&](int kt, int buf) {
        float4 b0 = *(const float4*)&wfc[(kt * 32 + kl) * IND + n0 + nq * 4];
        float4 b1 = *(const float4*)&wfc[(kt * 32 + 16 + kl) * IND + n0 + nq * 4];
        Bs[buf][nq * 4 + 0][kl] = (unsigned short)f2bf1(b0.x);
        Bs[buf][nq * 4 + 1][kl] = (unsigned short)f2bf1(b0.y);
        Bs[buf][nq * 4 + 2][kl] = (unsigned short)f2bf1(b0.z);
        Bs[buf][nq * 4 + 3][kl] = (unsigned short)f2bf1(b0.w);
        Bs[buf][nq * 4 + 0][kl + 16] = (unsigned short)f2bf1(b1.x);
        Bs[buf][nq * 4 + 1][kl + 16] = (unsigned short)f2bf1(b1.y);
        Bs[buf][nq * 4 + 2][kl + 16] = (unsigned short)f2bf1(b1.z);
        Bs[buf][nq * 4 + 3][kl + 16] = (unsigned short)f2bf1(b1.w);
    };
    stageB(0, 0);
    __syncthreads();
    #pragma unroll
    for (int kt = 0; kt < 8; kt++) {
        if (kt < 7) stageB(kt + 1, (kt + 1) & 1);
        const int buf = kt & 1;
        short8v a0 = *(const short8v*)&As[wm + fr][kt * 32 + fg * 8];
        short8v a1 = *(const short8v*)&As[wm + 16 + fr][kt * 32 + fg * 8];
        short8v b0 = *(const short8v*)&Bs[buf][wn + fr][fg * 8];
        short8v b1 = *(const short8v*)&Bs[buf][wn + 16 + fr][fg * 8];
        acc[0][0] = __builtin_amdgcn_mfma_f32_16x16x32_bf16(a0, b0, acc[0][0], 0, 0, 0);
        acc[0][1] = __builtin_amdgcn_mfma_f32_16x16x32_bf16(a0, b1, acc[0][1], 0, 0, 0);
        acc[1][0] = __builtin_amdgcn_mfma_f32_16x16x32_bf16(a1, b0, acc[1][0], 0, 0, 0);
        acc[1][1] = __builtin_amdgcn_mfma_f32_16x16x32_bf16(a1, b1, acc[1][1], 0, 0, 0);
        __syncthreads();
    }

    #pragma unroll
    for (int mi = 0; mi < 2; mi++)
        #pragma unroll
        for (int ni = 0; ni < 2; ni++)
            #pragma unroll
            for (int reg = 0; reg < 4; reg++) {
                int row = m0 + wm + mi * 16 + fg * 4 + reg;
                int col = n0 + wn + ni * 16 + fr;
                out[row * IND + col] = acc[mi][ni][reg] + xn[row * IND + col];
            }
}

extern "C" void kernel_launch(void* const* d_in, const int* in_sizes, int n_in,
                              void* d_out, int out_size, void* d_ws, size_t ws_size,
                              hipStream_t stream) {
    (void)in_sizes; (void)n_in; (void)out_size; (void)ws_size;
    const float* x     = (const float*)d_in[0];
    const float* w_q   = (const float*)d_in[1];
    const float* w_k   = (const float*)d_in[2];
    const float* w_v   = (const float*)d_in[3];
    const float* w_fc  = (const float*)d_in[4];
    const float* gamma = (const float*)d_in[5];
    const float* beta  = (const float*)d_in[6];
    float* out = (float*)d_out;

    float* ws = (float*)d_ws;
    float* xn = ws;                          // 2048*256 f32
    float* AO = xn + NTOK * IND;             // 2048*256 f32
    float* AM = AO + NTOK * IND;             // 2048 f32
    float* R  = AM + NTOK;                   // 32*512 f32 rowsums
    __half* Qh = (__half*)(R + BH * SEQ);    // 32*512*32 f16
    __half* Kh = Qh + BH * SEQ * DKV;        // 32*512*32 f16
    unsigned short* Vb16 = (unsigned short*)(Kh + BH * SEQ * DKV); // bf16 [bh][32][512]
    unsigned short* Pg = Vb16 + BH * SEQ * DKV; // bf16 [bh][512][512] e-values

    hipLaunchKernelGGL(lnproj_kernel, dim3(32, 12), dim3(256), 0, stream,
                       x, gamma, beta, w_q, w_k, w_v, xn, AM, R, Qh, Kh, Vb16);
    hipLaunchKernelGGL(attn_score_kernel, dim3(32, 32, 2), dim3(256), 0, stream,
                       Qh, Kh, Pg, R);
    hipLaunchKernelGGL(attn_pv_kernel, dim3(32, 32), dim3(256), 0, stream,
                       Pg, R, Vb16, AO, AM);
    hipLaunchKernelGGL(fcam_kernel, dim3(33, 4), dim3(256), 0, stream,
                       AO, w_fc, xn, AM, out, out + NTOK * IND);
}

// Round 11
// 75.299 us; speedup vs baseline: 1.1828x; 1.1828x over previous
//
#include <hip/hip_runtime.h>
#include <hip/hip_fp16.h>
#include <math.h>

#define BATCH 4
#define SEQ   512
#define IND   256
#define NH    8
#define DKV   32
#define BH    32   // BATCH*NH
#define NTOK  2048 // BATCH*SEQ

typedef __attribute__((ext_vector_type(8))) short short8v;
typedef __attribute__((ext_vector_type(4))) float floatx4;

__device__ __forceinline__ unsigned f2bf1(float f) {
    unsigned u = __builtin_bit_cast(unsigned, f);
    return (u + 0x7fffu + ((u >> 16) & 1u)) >> 16;
}
__device__ __forceinline__ unsigned f2bf2(float lo, float hi) {
    return f2bf1(lo) | (f2bf1(hi) << 16);
}
__device__ __forceinline__ __half2 habs2_(__half2 x) {
    unsigned u = __builtin_bit_cast(unsigned, x) & 0x7fff7fffu;
    return __builtin_bit_cast(__half2, u);
}
__device__ __forceinline__ __half2 shfl_xor_h2(__half2 x, int m) {
    float f = __builtin_bit_cast(float, x);
    f = __shfl_xor(f, m, 64);
    return __builtin_bit_cast(__half2, f);
}

// ============ Kernel 1: fused LayerNorm + Q/K/V projections (bf16 MFMA) =====
// grid (32, 12): x = 64-row tile, y: which = y>>2 (0=q,1=k,2=v), n0 = (y&3)*64
// Q,K,V: f16 [bh][l][32].   (identical to round-4 proven version)
__global__ __launch_bounds__(256) void lnproj_kernel(
        const float* __restrict__ x,
        const float* __restrict__ gamma, const float* __restrict__ beta,
        const float* __restrict__ wq, const float* __restrict__ wk,
        const float* __restrict__ wv,
        float* __restrict__ xn, float* __restrict__ am,
        __half* __restrict__ Q, __half* __restrict__ K, __half* __restrict__ V) {
    __shared__ __align__(16) unsigned short As[64][264];   // [m][k] bf16, full K
    __shared__ __align__(16) unsigned short Bs[2][64][40]; // [n][k] bf16, K-tile 32
    const int t = threadIdx.x;
    const int m0 = blockIdx.x * 64;
    const int y = blockIdx.y;
    const int which = y >> 2;
    const int n0 = (y & 3) * 64;
    const float* W = (which == 0) ? wq : (which == 1) ? wk : wv;
    __half* O = (which == 0) ? Q : (which == 1) ? K : V;

    // ---- Phase A: LayerNorm rows m0..m0+63 -> As (bf16) ----
    {
        const int r = t >> 2, q = t & 3;
        const float* xr = x + (m0 + r) * IND + q * 64;
        float4 xv[16];
        float s = 0.0f, s2 = 0.0f;
        #pragma unroll
        for (int i = 0; i < 16; i++) {
            xv[i] = *(const float4*)&xr[i * 4];
            s  += xv[i].x + xv[i].y + xv[i].z + xv[i].w;
            s2 += xv[i].x * xv[i].x + xv[i].y * xv[i].y
                + xv[i].z * xv[i].z + xv[i].w * xv[i].w;
        }
        s  += __shfl_xor(s, 1, 64);  s  += __shfl_xor(s, 2, 64);
        s2 += __shfl_xor(s2, 1, 64); s2 += __shfl_xor(s2, 2, 64);
        float mu = s * (1.0f / IND);
        float var = s2 * (1.0f / IND) - mu * mu;
        float rinv = rsqrtf(var + 1e-6f);
        const bool dox = (y == 0);
        if (dox && t < 64) am[m0 + t] = 0.0f;
        #pragma unroll
        for (int i = 0; i < 8; i++) {
            float4 a = xv[2 * i], bv = xv[2 * i + 1];
            float4 g0 = *(const float4*)&gamma[q * 64 + i * 8];
            float4 g1 = *(const float4*)&gamma[q * 64 + i * 8 + 4];
            float4 b0 = *(const float4*)&beta[q * 64 + i * 8];
            float4 b1 = *(const float4*)&beta[q * 64 + i * 8 + 4];
            float4 n0v, n1v;
            n0v.x = (a.x - mu) * rinv * g0.x + b0.x;
            n0v.y = (a.y - mu) * rinv * g0.y + b0.y;
            n0v.z = (a.z - mu) * rinv * g0.z + b0.z;
            n0v.w = (a.w - mu) * rinv * g0.w + b0.w;
            n1v.x = (bv.x - mu) * rinv * g1.x + b1.x;
            n1v.y = (bv.y - mu) * rinv * g1.y + b1.y;
            n1v.z = (bv.z - mu) * rinv * g1.z + b1.z;
            n1v.w = (bv.w - mu) * rinv * g1.w + b1.w;
            if (dox) {
                *(float4*)&xn[(m0 + r) * IND + q * 64 + i * 8] = n0v;
                *(float4*)&xn[(m0 + r) * IND + q * 64 + i * 8 + 4] = n1v;
            }
            uint4 pk;
            pk.x = f2bf2(n0v.x, n0v.y); pk.y = f2bf2(n0v.z, n0v.w);
            pk.z = f2bf2(n1v.x, n1v.y); pk.w = f2bf2(n1v.z, n1v.w);
            *(uint4*)&As[r][q * 64 + i * 8] = pk;
        }
    }

    // ---- Phase B: MFMA over K (B double-buffered per 32-k tile) ----
    const int w = t >> 6, l = t & 63;
    const int wm = (w >> 1) * 32, wn = (w & 1) * 32;
    const int fr = l & 15, fg = l >> 4;
    floatx4 acc[2][2];
    #pragma unroll
    for (int i = 0; i < 2; i++)
        #pragma unroll
        for (int j = 0; j < 2; j++) acc[i][j] = (floatx4)(0.0f);

    const int kl = t >> 4, nq = t & 15;
    auto stageB = [&](int kt, int buf) {
        float4 b0 = *(const float4*)&W[(kt * 32 + kl) * IND + n0 + nq * 4];
        float4 b1 = *(const float4*)&W[(kt * 32 + 16 + kl) * IND + n0 + nq * 4];
        Bs[buf][nq * 4 + 0][kl] = (unsigned short)f2bf1(b0.x);
        Bs[buf][nq * 4 + 1][kl] = (unsigned short)f2bf1(b0.y);
        Bs[buf][nq * 4 + 2][kl] = (unsigned short)f2bf1(b0.z);
        Bs[buf][nq * 4 + 3][kl] = (unsigned short)f2bf1(b0.w);
        Bs[buf][nq * 4 + 0][kl + 16] = (unsigned short)f2bf1(b1.x);
        Bs[buf][nq * 4 + 1][kl + 16] = (unsigned short)f2bf1(b1.y);
        Bs[buf][nq * 4 + 2][kl + 16] = (unsigned short)f2bf1(b1.z);
        Bs[buf][nq * 4 + 3][kl + 16] = (unsigned short)f2bf1(b1.w);
    };
    stageB(0, 0);
    __syncthreads();
    #pragma unroll
    for (int kt = 0; kt < 8; kt++) {
        if (kt < 7) stageB(kt + 1, (kt + 1) & 1);
        const int buf = kt & 1;
        short8v a0 = *(const short8v*)&As[wm + fr][kt * 32 + fg * 8];
        short8v a1 = *(const short8v*)&As[wm + 16 + fr][kt * 32 + fg * 8];
        short8v b0 = *(const short8v*)&Bs[buf][wn + fr][fg * 8];
        short8v b1 = *(const short8v*)&Bs[buf][wn + 16 + fr][fg * 8];
        acc[0][0] = __builtin_amdgcn_mfma_f32_16x16x32_bf16(a0, b0, acc[0][0], 0, 0, 0);
        acc[0][1] = __builtin_amdgcn_mfma_f32_16x16x32_bf16(a0, b1, acc[0][1], 0, 0, 0);
        acc[1][0] = __builtin_amdgcn_mfma_f32_16x16x32_bf16(a1, b0, acc[1][0], 0, 0, 0);
        acc[1][1] = __builtin_amdgcn_mfma_f32_16x16x32_bf16(a1, b1, acc[1][1], 0, 0, 0);
        __syncthreads();
    }

    // ---- Epilogue: scale (q only), f16 store to [bh][l][32] ----
    const float scale = (which == 0) ? 0.17677669529663687f : 1.0f;
    #pragma unroll
    for (int mi = 0; mi < 2; mi++)
        #pragma unroll
        for (int ni = 0; ni < 2; ni++)
            #pragma unroll
            for (int reg = 0; reg < 4; reg++) {
                int row = m0 + wm + mi * 16 + fg * 4 + reg;   // token
                int col = n0 + wn + ni * 16 + fr;             // 0..255
                int b = row >> 9, ll = row & 511;
                int h = col >> 5, d = col & 31;
                O[(((b << 3) + h) * SEQ + ll) * DKV + d] =
                    __float2half_rn(acc[mi][ni][reg] * scale);
            }
}

// ============ Kernel 2: attention — R4 engine, 8-row i-tiles for occupancy ===
// grid (64, 32): x = 8-row i-tile, y = bh; block 256 = 4 waves.
// Thread (g=t>>5, jl=t&31) owns row i0+g, j = tile*128 + m*32 + jl.
__global__ __launch_bounds__(256) void attn_kernel(
        const __half* __restrict__ Qh, const __half* __restrict__ Kh,
        const __half* __restrict__ Vh, float* __restrict__ attn_out,
        float* __restrict__ am) {
    __shared__ __align__(16) __half Th[2][128][40];
    const int t = threadIdx.x;
    const int gy = blockIdx.y;
    const int i0 = blockIdx.x * 8;
    const int b = gy >> 3, h = gy & 7;
    const __half* Qb = Qh + gy * SEQ * DKV;
    const __half* Kb = Kh + gy * SEQ * DKV;
    const __half* Vb = Vh + gy * SEQ * DKV;
    const int g = t >> 5, jl = t & 31;
    const int r0 = t >> 2, ch = t & 3;

    // K row (i0+g) in registers as half2
    __half2 ka[16];
    {
        const float4* pa = (const float4*)(Kb + (i0 + g) * DKV);
        #pragma unroll
        for (int c = 0; c < 4; c++) {
            float4 va = pa[c];
            const __half2* ha = (const __half2*)&va;
            #pragma unroll
            for (int k = 0; k < 4; k++) ka[c*4+k] = ha[k];
        }
    }

    float vals_a[16];
    float4 pre0, pre1;

    // ---- Phase 1: scores (Q tiles of 128 rows, double-buffered) ----
    pre0 = *(const float4*)(Qb + r0 * DKV + ch * 8);
    pre1 = *(const float4*)(Qb + (r0 + 64) * DKV + ch * 8);
    *(float4*)&Th[0][r0][ch * 8] = pre0;
    *(float4*)&Th[0][r0 + 64][ch * 8] = pre1;
    __syncthreads();
    #pragma unroll
    for (int tile = 0; tile < 4; tile++) {
        const int buf = tile & 1;
        if (tile < 3) {
            pre0 = *(const float4*)(Qb + ((tile+1)*128 + r0) * DKV + ch * 8);
            pre1 = *(const float4*)(Qb + ((tile+1)*128 + r0 + 64) * DKV + ch * 8);
        }
        #pragma unroll
        for (int m = 0; m < 4; m++) {
            const int j = jl + m * 32;
            __half2 z = __float2half2_rn(0.0f);
            __half2 sa0 = z, sa1 = z;
            #pragma unroll
            for (int c = 0; c < 4; c++) {
                float4 qv = *(const float4*)&Th[buf][j][c * 8];
                const __half2* q2 = (const __half2*)&qv;
                #pragma unroll
                for (int k = 0; k < 4; k++) {
                    __half2 da = habs2_(__hsub2(q2[k], ka[c*4+k]));
                    if (k & 1) sa1 = __hadd2(sa1, da);
                    else       sa0 = __hadd2(sa0, da);
                }
            }
            __half2 sa = __hadd2(sa0, sa1);
            vals_a[tile*4+m] = (__low2float(sa) + __high2float(sa)) * (1.0f/32.0f);
        }
        if (tile < 3) {
            *(float4*)&Th[buf ^ 1][r0][ch * 8] = pre0;
            *(float4*)&Th[buf ^ 1][r0 + 64][ch * 8] = pre1;
        }
        __syncthreads();
    }

    // ---- Phase 2: softmax over j (32 jl lanes per row) ----
    float mxa = vals_a[0];
    #pragma unroll
    for (int m = 1; m < 16; m++) mxa = fmaxf(mxa, vals_a[m]);
    #pragma unroll
    for (int s = 1; s <= 16; s <<= 1)
        mxa = fmaxf(mxa, __shfl_xor(mxa, s, 64));
    float sua = 0.0f;
    #pragma unroll
    for (int m = 0; m < 16; m++) {
        vals_a[m] = __expf(vals_a[m] - mxa); sua += vals_a[m];
    }
    #pragma unroll
    for (int s = 1; s <= 16; s <<= 1)
        sua += __shfl_xor(sua, s, 64);
    float inva = 1.0f / sua;
    #pragma unroll
    for (int m = 0; m < 16; m++) vals_a[m] *= inva;

    // ---- Phase 3: PV (V tiles of 128 rows, double-buffered, packed hfma2) ----
    __half2 acc_a[16];
    #pragma unroll
    for (int k = 0; k < 16; k++) acc_a[k] = __float2half2_rn(0.0f);
    pre0 = *(const float4*)(Vb + r0 * DKV + ch * 8);
    pre1 = *(const float4*)(Vb + (r0 + 64) * DKV + ch * 8);
    *(float4*)&Th[0][r0][ch * 8] = pre0;
    *(float4*)&Th[0][r0 + 64][ch * 8] = pre1;
    __syncthreads();
    #pragma unroll
    for (int tile = 0; tile < 4; tile++) {
        const int buf = tile & 1;
        if (tile < 3) {
            pre0 = *(const float4*)(Vb + ((tile+1)*128 + r0) * DKV + ch * 8);
            pre1 = *(const float4*)(Vb + ((tile+1)*128 + r0 + 64) * DKV + ch * 8);
        }
        #pragma unroll
        for (int m = 0; m < 4; m++) {
            const int j = jl + m * 32;
            __half2 pa = __float2half2_rn(vals_a[tile*4+m]);
            #pragma unroll
            for (int c = 0; c < 4; c++) {
                float4 vv = *(const float4*)&Th[buf][j][c * 8];
                const __half2* v2 = (const __half2*)&vv;
                #pragma unroll
                for (int k = 0; k < 4; k++)
                    acc_a[c*4+k] = __hfma2(pa, v2[k], acc_a[c*4+k]);
            }
        }
        if (tile < 3) {
            *(float4*)&Th[buf ^ 1][r0][ch * 8] = pre0;
            *(float4*)&Th[buf ^ 1][r0 + 64][ch * 8] = pre1;
        }
        __syncthreads();
    }

    // ---- O reduction across 32 j-lanes (butterfly) ----
#define REDSTEP(S, C)                                                      \
    {                                                                      \
        _Pragma("unroll")                                                  \
        for (int k = 0; k < (C); k++) {                                    \
            __half2 sa = (jl & (S)) ? acc_a[k] : acc_a[k + (C)];           \
            __half2 ra = shfl_xor_h2(sa, (S));                             \
            __half2 qa = (jl & (S)) ? acc_a[k + (C)] : acc_a[k];           \
            acc_a[k] = __hadd2(qa, ra);                                    \
        }                                                                  \
    }
    REDSTEP(16, 8)
    REDSTEP(8, 4)
    REDSTEP(4, 2)
    REDSTEP(2, 1)
#undef REDSTEP
    acc_a[0] = __hadd2(acc_a[0], shfl_xor_h2(acc_a[0], 1));
    if (!(jl & 1)) {
        int d2 = (jl >> 1) & 15;
        int col = h * 32 + d2 * 2;
        float2 oa = make_float2(__low2float(acc_a[0]), __high2float(acc_a[0]));
        *(float2*)&attn_out[(b * SEQ + i0 + g) * IND + col] = oa;
    }

    // ---- am column sums (row-pair combine -> LDS across waves -> atomics) ----
    float colp[16];
    #pragma unroll
    for (int m = 0; m < 16; m++) {
        float cp = vals_a[m];
        cp += __shfl_xor(cp, 32, 64);   // combine rows g and g^1
        colp[m] = cp;
    }
    float* amw = (float*)&Th[0][0][0];
    const int w = t >> 6;
    if (!(t & 32)) {
        #pragma unroll
        for (int m = 0; m < 16; m++) {
            int j = (m >> 2) * 128 + (m & 3) * 32 + jl;
            amw[w * 512 + j] = colp[m];
        }
    }
    __syncthreads();
    #pragma unroll
    for (int n = 0; n < 2; n++) {
        int j = t + n * 256;
        float s = (amw[j] + amw[512 + j] + amw[1024 + j] + amw[1536 + j]) * 0.125f;
        atomicAdd(&am[b * SEQ + j], s);
    }
}

// ============ Kernel 3: FC(bf16 MFMA) + residual, + fused amnorm ============
// grid (33, 4): x<32 -> GEMM tile (m0=x*64, n0=y*64); x==32 -> amnorm batch y
__global__ __launch_bounds__(256) void fcam_kernel(
        const float* __restrict__ ao, const float* __restrict__ wfc,
        const float* __restrict__ xn, const float* __restrict__ am,
        float* __restrict__ out, float* __restrict__ out_am) {
    __shared__ __align__(16) unsigned short As[64][264];
    __shared__ __align__(16) unsigned short Bs[2][64][40];
    __shared__ float lmn[4], lmx[4];
    const int t = threadIdx.x;

    if (blockIdx.x == 32) {   // ---- amnorm for batch blockIdx.y ----
        int b = blockIdx.y;
        float v0 = am[b * SEQ + t];
        float v1 = am[b * SEQ + t + 256];
        float mn = fminf(v0, v1), mx = fmaxf(v0, v1);
        #pragma unroll
        for (int o = 32; o > 0; o >>= 1) {
            mn = fminf(mn, __shfl_xor(mn, o, 64));
            mx = fmaxf(mx, __shfl_xor(mx, o, 64));
        }
        int w = t >> 6;
        if ((t & 63) == 0) { lmn[w] = mn; lmx[w] = mx; }
        __syncthreads();
        mn = fminf(fminf(lmn[0], lmn[1]), fminf(lmn[2], lmn[3]));
        mx = fmaxf(fmaxf(lmx[0], lmx[1]), fmaxf(lmx[2], lmx[3]));
        float inv = 1.0f / (mx - mn);
        out_am[b * SEQ + t]       = (v0 - mn) * inv;
        out_am[b * SEQ + t + 256] = (v1 - mn) * inv;
        return;
    }

    const int m0 = blockIdx.x * 64;
    const int n0 = blockIdx.y * 64;

    {
        const int r = t >> 2, q = t & 3;
        const float* ar = ao + (m0 + r) * IND + q * 64;
        #pragma unroll
        for (int i = 0; i < 8; i++) {
            float4 a = *(const float4*)&ar[i * 8];
            float4 bv = *(const float4*)&ar[i * 8 + 4];
            uint4 pk;
            pk.x = f2bf2(a.x, a.y);  pk.y = f2bf2(a.z, a.w);
            pk.z = f2bf2(bv.x, bv.y); pk.w = f2bf2(bv.z, bv.w);
            *(uint4*)&As[r][q * 64 + i * 8] = pk;
        }
    }

    const int w = t >> 6, l = t & 63;
    const int wm = (w >> 1) * 32, wn = (w & 1) * 32;
    const int fr = l & 15, fg = l >> 4;
    floatx4 acc[2][2];
    #pragma unroll
    for (int i = 0; i < 2; i++)
        #pragma unroll
        for (int j = 0; j < 2; j++) acc[i][j] = (floatx4)(0.0f);

    const int kl = t >> 4, nq = t & 15;
    auto stageB = [&](int kt, int buf) {
        float4 b0 = *(const float4*)&wfc[(kt * 32 + kl) * IND + n0 + nq * 4];
        float4 b1 = *(const float4*)&wfc[(kt * 32 + 16 + kl) * IND + n0 + nq * 4];
        Bs[buf][nq * 4 + 0][kl] = (unsigned short)f2bf1(b0.x);
        Bs[buf][nq * 4 + 1][kl] = (unsigned short)f2bf1(b0.y);
        Bs[buf][nq * 4 + 2][kl] = (unsigned short)f2bf1(b0.z);
        Bs[buf][nq * 4 + 3][kl] = (unsigned short)f2bf1(b0.w);
        Bs[buf][nq * 4 + 0][kl + 16] = (unsigned short)f2bf1(b1.x);
        Bs[buf][nq * 4 + 1][kl + 16] = (unsigned short)f2bf1(b1.y);
        Bs[buf][nq * 4 + 2][kl + 16] = (unsigned short)f2bf1(b1.z);
        Bs[buf][nq * 4 + 3][kl + 16] = (unsigned short)f2bf1(b1.w);
    };
    stageB(0, 0);
    __syncthreads();
    #pragma unroll
    for (int kt = 0; kt < 8; kt++) {
        if (kt < 7) stageB(kt + 1, (kt + 1) & 1);
        const int buf = kt & 1;
        short8v a0 = *(const short8v*)&As[wm + fr][kt * 32 + fg * 8];
        short8v a1 = *(const short8v*)&As[wm + 16 + fr][kt * 32 + fg * 8];
        short8v b0 = *(const short8v*)&Bs[buf][wn + fr][fg * 8];
        short8v b1 = *(const short8v*)&Bs[buf][wn + 16 + fr][fg * 8];
        acc[0][0] = __builtin_amdgcn_mfma_f32_16x16x32_bf16(a0, b0, acc[0][0], 0, 0, 0);
        acc[0][1] = __builtin_amdgcn_mfma_f32_16x16x32_bf16(a0, b1, acc[0][1], 0, 0, 0);
        acc[1][0] = __builtin_amdgcn_mfma_f32_16x16x32_bf16(a1, b0, acc[1][0], 0, 0, 0);
        acc[1][1] = __builtin_amdgcn_mfma_f32_16x16x32_bf16(a1, b1, acc[1][1], 0, 0, 0);
        __syncthreads();
    }

    #pragma unroll
    for (int mi = 0; mi < 2; mi++)
        #pragma unroll
        for (int ni = 0; ni < 2; ni++)
            #pragma unroll
            for (int reg = 0; reg < 4; reg++) {
                int row = m0 + wm + mi * 16 + fg * 4 + reg;
                int col = n0 + wn + ni * 16 + fr;
                out[row * IND + col] = acc[mi][ni][reg] + xn[row * IND + col];
            }
}

extern "C" void kernel_launch(void* const* d_in, const int* in_sizes, int n_in,
                              void* d_out, int out_size, void* d_ws, size_t ws_size,
                              hipStream_t stream) {
    (void)in_sizes; (void)n_in; (void)out_size; (void)ws_size;
    const float* x     = (const float*)d_in[0];
    const float* w_q   = (const float*)d_in[1];
    const float* w_k   = (const float*)d_in[2];
    const float* w_v   = (const float*)d_in[3];
    const float* w_fc  = (const float*)d_in[4];
    const float* gamma = (const float*)d_in[5];
    const float* beta  = (const float*)d_in[6];
    float* out = (float*)d_out;

    float* ws = (float*)d_ws;
    float* xn = ws;                          // 2048*256 f32
    float* AO = xn + NTOK * IND;             // 2048*256 f32
    float* AM = AO + NTOK * IND;             // 2048 f32
    __half* Qh = (__half*)(AM + NTOK);       // 32*512*32 f16
    __half* Kh = Qh + BH * SEQ * DKV;        // 32*512*32 f16
    __half* Vh = Kh + BH * SEQ * DKV;        // 32*512*32 f16

    hipLaunchKernelGGL(lnproj_kernel, dim3(32, 12), dim3(256), 0, stream,
                       x, gamma, beta, w_q, w_k, w_v, xn, AM, Qh, Kh, Vh);
    hipLaunchKernelGGL(attn_kernel, dim3(64, 32), dim3(256), 0, stream,
                       Qh, Kh, Vh, AO, AM);
    hipLaunchKernelGGL(fcam_kernel, dim3(33, 4), dim3(256), 0, stream,
                       AO, w_fc, xn, AM, out, out + NTOK * IND);
}